// Round 10
// baseline (35.696 us; speedup 1.0000x reference)
//
#include <hip/hip_runtime.h>

#define G 64
#define TT 4096
#define EDGES 131072
#define HALF 65536

#define OUT_ETOT 0
#define OUT_NODEE 64
#define OUT_Q (64 + 4096)
#define OUT_NF (64 + 4096 + 4096)

typedef unsigned long long ull;

__device__ __forceinline__ float wave_sum_f(float v) {
#pragma unroll
    for (int m = 1; m < 64; m <<= 1) v += __shfl_xor(v, m);
    return v;
}
__device__ __forceinline__ double wave_sum_d(double v) {
#pragma unroll
    for (int m = 1; m < 64; m <<= 1) v += __shfl_xor(v, m);
    return v;
}
__device__ __forceinline__ double bcast_d(double v, int j) {
    union { double d; int i[2]; } u;
    u.d = v;
    union { int i[2]; double d; } r;
    r.i[0] = __builtin_amdgcn_readlane(u.i[0], j);
    r.i[1] = __builtin_amdgcn_readlane(u.i[1], j);
    return r.d;
}
__device__ __forceinline__ int type_of(float4 na) {
    int t = 0;
    float best = na.x;
    if (na.y > best) { best = na.y; t = 1; }
    if (na.z > best) { best = na.z; t = 2; }
    if (na.w > best) { best = na.w; t = 3; }
    return t;
}
__device__ __forceinline__ float fcut(float R, float c1) {
    if (R < 1.0f) return c1;             // R is always > 0 here
    if (R > 6.0f) return 0.0f;
    float x = 1.0f - (R - 1.0f) * 0.2f;  // in [0,1]
    float ex = __expf(2.0f * x);
    float t = (ex - 1.0f) / (ex + 1.0f); // tanh(x)
    return t * t * t;
}

// One block per graph. Phases:
//  A: zero LDS packed table
//  B: scan first half of edge list; LDS atomicMax (tag = edge idx; mirrored
//     second-half edge emitted as tag e+HALF) == np last-write-wins
//  C: build factor / factor*Fc in LDS + E2b row sums (all 16 waves)
//  D: wave 0: fp64 dual forward substitution; waves 1-15: node_feats copy
//  E: matvec row sums + epilogue (block-local E_tot, no atomics)
// sum(q)=0 per graph exactly (constraint row), so the cross-graph "off"
// term is O(solver eps) and dropped -> graphs fully independent.
__global__ __launch_bounds__(1024, 1) void k_main(
    const int* __restrict__ ei, const float* __restrict__ elen,
    const float* __restrict__ node_attrs, const float* __restrict__ kappa,
    const float* __restrict__ ref_eta, const float* __restrict__ ref_log_sigma,
    const float* __restrict__ ref_A, const float* __restrict__ ref_B,
    const float* __restrict__ ref_C, const float* __restrict__ ref_D,
    const float* __restrict__ ref_mu, const float* __restrict__ short_e,
    const float* __restrict__ atomic_short, const float* __restrict__ nf_in,
    float* __restrict__ out) {
    __shared__ ull s_pack[4096];   // 32 KB per-graph cell table
    __shared__ float sL[64][65];   // factor
    __shared__ float sF[64][65];   // factor * Fc
    __shared__ float s_diag[64];
    __shared__ float s_q[64];
    __shared__ float s_ash[64];
    __shared__ float s_red[16];

    const int g = blockIdx.x;
    const int tid = threadIdx.x;
    const int lane = tid & 63;
    const int wv = tid >> 6;               // 0..15; rows wv*4..wv*4+3
    const float SQRT_PI = 1.7724538509055159f;
    const float th1 = tanhf(1.0f);
    const float c1 = th1 * th1 * th1;

    // ---- phase A: zero packed table; per-lane type/sigma --------------------
#pragma unroll
    for (int k = 0; k < 4; ++k) s_pack[tid + k * 1024] = 0ull;
    const float4 na = *(const float4*)(node_attrs + ((size_t)((g << 6) + lane) << 2));
    const int tj = type_of(na);
    const float sgj = __expf(ref_log_sigma[tj]);
    if (tid < 64) {                         // wave 0: lane == tid
        s_diag[tid] = ref_eta[tj] + 1.0f / (sgj * SQRT_PI);
        s_ash[tid] = atomic_short[(g << 6) + tid];
    }
    __syncthreads();

    // ---- phase B: edge scan -> LDS atomicMax --------------------------------
#pragma unroll 4
    for (int e = tid; e < HALF; e += 1024) {
        int i = ei[e];
        int j = ei[EDGES + e];
        float R = elen[e];                  // in [1,6] -> bits > 0
        if ((i >> 6) == g) {                // i and j always in same graph
            ull rb = (ull)__float_as_uint(R);
            atomicMax(&s_pack[((i & 63) << 6) + (j & 63)],
                      ((ull)(unsigned)e << 32) | rb);
            atomicMax(&s_pack[((j & 63) << 6) + (i & 63)],
                      ((ull)(unsigned)(e + HALF) << 32) | rb);
        }
    }
    __syncthreads();

    // ---- phase C: build factor / factor*Fc; E2b row sums --------------------
    float e2b[4];
#pragma unroll
    for (int r = 0; r < 4; ++r) {
        const int row = (wv << 2) + r;
        const ull pk = s_pack[(row << 6) + lane];
        const int ti = __shfl(tj, row);
        const float sgi = __shfl(sgj, row);
        const float gam = sqrtf(sgi * sgi + sgj * sgj);
        const float R = (pk > 0ull) ? __uint_as_float((unsigned)pk) : 0.5f;
        const float rinv = __frcp_rn(R);
        const float factor = erff(R * (0.70710678118654752f / gam)) * rinv;
        const float fc = fcut(R, c1);
        sL[row][lane] = factor;
        sF[row][lane] = factor * fc;
        float e = 0.0f;
        if (row != lane) {
            int t4 = ti * 4 + tj;
            float r2 = rinv * rinv;
            float r6 = r2 * r2 * r2;
            e = (ref_A[t4] * __expf(ref_B[t4] * (ref_mu[t4] - R)) -
                 ref_C[t4] * r6 - ref_D[t4] * (r6 * r2)) * fc;
        }
        e2b[r] = e;
    }
#pragma unroll
    for (int m = 1; m < 64; m <<= 1) {
#pragma unroll
        for (int r = 0; r < 4; ++r) e2b[r] += __shfl_xor(e2b[r], m);
    }
    __syncthreads();

    // ---- phase D: wave 0 solves (fp64); waves 1-15 copy node_feats ----------
    if (wv == 0) {
        const int i = tid;
        double Ld = (double)(s_diag[i] + sL[i][i]);
        double inv = 1.0 / Ld;
        double au = 1.0;
        double av = (double)kappa[(g << 6) + i];
        double my_u = 0.0, my_v = 0.0;
        for (int j = 0; j < 64; ++j) {
            double ij = bcast_d(inv, j);
            double uj = bcast_d(au, j) * ij;
            double vj = bcast_d(av, j) * ij;
            if (i == j) { my_u = uj; my_v = vj; }
            if (i > j) {
                double Lij = (double)sL[i][j];
                au -= Lij * uj;
                av -= Lij * vj;
            }
        }
        double Su = wave_sum_d(my_u);
        double Sv = wave_sum_d(my_v);
        double lam = Sv / Su;  // q = -v + (Sv/Su)u  => sum(q) = 0
        s_q[i] = (float)(-my_v + lam * my_u);
    } else {
        // 4096 float2 per graph (64 rows x 64 float2), 960 threads
        for (int t2 = tid - 64; t2 < 4096; t2 += 960) {
            int row = t2 >> 6, c = t2 & 63;
            float2 v = ((const float2*)nf_in)[(((g << 6) + row) << 6) + c];
            *(float2*)(out + OUT_NF + (size_t)((g << 6) + row) * 130 + c * 2) = v;
        }
    }
    __syncthreads();

    // ---- phase E: matvec row sums + epilogue --------------------------------
    const float qj = s_q[lane];
    float pr[4], wr[4];
#pragma unroll
    for (int r = 0; r < 4; ++r) {
        const int row = (wv << 2) + r;
        pr[r] = sF[row][lane] * qj;
        wr[r] = sL[row][lane] * qj;
    }
#pragma unroll
    for (int m = 1; m < 64; m <<= 1) {
#pragma unroll
        for (int r = 0; r < 4; ++r) {
            pr[r] += __shfl_xor(pr[r], m);
            wr[r] += __shfl_xor(wr[r], m);
        }
    }
    float acc = 0.0f;
#pragma unroll
    for (int r = 0; r < 4; ++r) {
        const int row = (wv << 2) + r;
        const float q = s_q[row];
        const float sgi = __shfl(sgj, row);
        if (lane == 0) {
            float coef = 0.5f / (sgi * SQRT_PI);
            float aEel = q * (wr[r] + coef * q);
            float e2 = 0.5f * e2b[r];
            out[OUT_NODEE + (g << 6) + row] = aEel + e2 + s_ash[row];
            out[OUT_Q + (g << 6) + row] = q;
            size_t nfb = OUT_NF + (size_t)((g << 6) + row) * 130;
            out[nfb + 128] = q;
            out[nfb + 129] = pr[r];
            acc += aEel + e2;
        }
    }
    if (lane == 0) s_red[wv] = acc;
    __syncthreads();
    if (tid == 0) {
        float s = 0.0f;
#pragma unroll
        for (int k = 0; k < 16; ++k) s += s_red[k];
        out[OUT_ETOT + g] = s + short_e[g];
    }
}

extern "C" void kernel_launch(void* const* d_in, const int* in_sizes, int n_in,
                              void* d_out, int out_size, void* d_ws, size_t ws_size,
                              hipStream_t stream) {
    const float* node_attrs = (const float*)d_in[1];
    const int* edge_index = (const int*)d_in[2];
    const float* edge_length = (const float*)d_in[3];
    const float* kappa = (const float*)d_in[4];
    const float* node_feats = (const float*)d_in[5];
    const float* ref_eta = (const float*)d_in[6];
    const float* ref_log_sigma = (const float*)d_in[7];
    const float* ref_A = (const float*)d_in[8];
    const float* ref_B = (const float*)d_in[9];
    const float* ref_C = (const float*)d_in[10];
    const float* ref_D = (const float*)d_in[11];
    const float* ref_mu = (const float*)d_in[12];
    const float* short_energy = (const float*)d_in[13];
    const float* atomic_short = (const float*)d_in[14];

    k_main<<<G, 1024, 0, stream>>>(edge_index, edge_length, node_attrs, kappa,
                                   ref_eta, ref_log_sigma, ref_A, ref_B, ref_C,
                                   ref_D, ref_mu, short_energy, atomic_short,
                                   node_feats, (float*)d_out);
}

// Round 11
// 28.702 us; speedup vs baseline: 1.2437x; 1.2437x over previous
//
#include <hip/hip_runtime.h>

#define G 64
#define TT 4096
#define EDGES 131072
#define HALF 65536

#define OUT_ETOT 0
#define OUT_NODEE 64
#define OUT_Q (64 + 4096)
#define OUT_NF (64 + 4096 + 4096)

typedef unsigned long long ull;

__device__ __forceinline__ float wave_sum_f(float v) {
#pragma unroll
    for (int m = 1; m < 64; m <<= 1) v += __shfl_xor(v, m);
    return v;
}
__device__ __forceinline__ double wave_sum_d(double v) {
#pragma unroll
    for (int m = 1; m < 64; m <<= 1) v += __shfl_xor(v, m);
    return v;
}
__device__ __forceinline__ double bcast_d(double v, int j) {
    union { double d; int i[2]; } u;
    u.d = v;
    union { int i[2]; double d; } r;
    r.i[0] = __builtin_amdgcn_readlane(u.i[0], j);
    r.i[1] = __builtin_amdgcn_readlane(u.i[1], j);
    return r.d;
}
__device__ __forceinline__ int type_of(float4 na) {
    int t = 0;
    float best = na.x;
    if (na.y > best) { best = na.y; t = 1; }
    if (na.z > best) { best = na.z; t = 2; }
    if (na.w > best) { best = na.w; t = 3; }
    return t;
}
__device__ __forceinline__ float fcut(float R, float c1) {
    if (R < 1.0f) return c1;             // R is always > 0 here
    if (R > 6.0f) return 0.0f;
    float x = 1.0f - (R - 1.0f) * 0.2f;  // in [0,1]
    float ex = __expf(2.0f * x);
    float t = (ex - 1.0f) / (ex + 1.0f); // tanh(x)
    return t * t * t;
}

// One block per graph; single dispatch. Phases:
//  A: zero LDS packed table
//  B: VECTORIZED edge scan (4 edges/thread/iter, int4/float4); LDS atomicMax
//     (tag = edge idx; mirror tagged e+HALF) == np last-write-wins semantics
//  C: build factor / factor*Fc in LDS + E2b row sums (16 waves)
//  D: wave 0: fp64 dual forward substitution; waves 1-15: node_feats copy
//  E: matvec row sums + epilogue (block-local E_tot, no atomics)
// sum(q)=0 per graph exactly (constraint row), so the cross-graph "off"
// term is O(solver eps) and dropped -> graphs fully independent.
__global__ __launch_bounds__(1024, 1) void k_main(
    const int* __restrict__ ei, const float* __restrict__ elen,
    const float* __restrict__ node_attrs, const float* __restrict__ kappa,
    const float* __restrict__ ref_eta, const float* __restrict__ ref_log_sigma,
    const float* __restrict__ ref_A, const float* __restrict__ ref_B,
    const float* __restrict__ ref_C, const float* __restrict__ ref_D,
    const float* __restrict__ ref_mu, const float* __restrict__ short_e,
    const float* __restrict__ atomic_short, const float* __restrict__ nf_in,
    float* __restrict__ out) {
    __shared__ ull s_pack[4096];   // 32 KB per-graph cell table
    __shared__ float sL[64][65];   // factor
    __shared__ float sF[64][65];   // factor * Fc
    __shared__ float s_diag[64];
    __shared__ float s_q[64];
    __shared__ float s_ash[64];
    __shared__ float s_red[16];

    const int g = blockIdx.x;
    const int tid = threadIdx.x;
    const int lane = tid & 63;
    const int wv = tid >> 6;               // 0..15; rows wv*4..wv*4+3
    const float SQRT_PI = 1.7724538509055159f;
    const float th1 = tanhf(1.0f);
    const float c1 = th1 * th1 * th1;

    // ---- phase A: zero packed table; per-lane type/sigma --------------------
#pragma unroll
    for (int k = 0; k < 4; ++k) s_pack[tid + k * 1024] = 0ull;
    const float4 na = *(const float4*)(node_attrs + ((size_t)((g << 6) + lane) << 2));
    const int tj = type_of(na);
    const float sgj = __expf(ref_log_sigma[tj]);
    if (tid < 64) {                         // wave 0: lane == tid
        s_diag[tid] = ref_eta[tj] + 1.0f / (sgj * SQRT_PI);
        s_ash[tid] = atomic_short[(g << 6) + tid];
    }
    __syncthreads();

    // ---- phase B: vectorized edge scan -> LDS atomicMax ---------------------
    {
        const int4* src4 = (const int4*)ei;
        const int4* dst4 = (const int4*)(ei + EDGES);
        const float4* len4 = (const float4*)elen;
#pragma unroll 2
        for (int b = tid; b < HALF / 4; b += 1024) {
            const int4 si = src4[b];
            const int4 dj = dst4[b];
            const float4 rr = len4[b];
            const int e0 = b << 2;
            int iv[4] = { si.x, si.y, si.z, si.w };
            int jv[4] = { dj.x, dj.y, dj.z, dj.w };
            float Rv[4] = { rr.x, rr.y, rr.z, rr.w };
#pragma unroll
            for (int k = 0; k < 4; ++k) {
                if ((iv[k] >> 6) == g) {
                    const ull rb = (ull)__float_as_uint(Rv[k]);
                    const int e = e0 + k;
                    atomicMax(&s_pack[((iv[k] & 63) << 6) + (jv[k] & 63)],
                              ((ull)(unsigned)e << 32) | rb);
                    atomicMax(&s_pack[((jv[k] & 63) << 6) + (iv[k] & 63)],
                              ((ull)(unsigned)(e + HALF) << 32) | rb);
                }
            }
        }
    }
    __syncthreads();

    // ---- phase C: build factor / factor*Fc; E2b row sums --------------------
    float e2b[4];
#pragma unroll
    for (int r = 0; r < 4; ++r) {
        const int row = (wv << 2) + r;
        const ull pk = s_pack[(row << 6) + lane];
        const int ti = __shfl(tj, row);
        const float sgi = __shfl(sgj, row);
        const float gam = sqrtf(sgi * sgi + sgj * sgj);
        const float R = (pk > 0ull) ? __uint_as_float((unsigned)pk) : 0.5f;
        const float rinv = __frcp_rn(R);
        const float factor = erff(R * (0.70710678118654752f / gam)) * rinv;
        const float fc = fcut(R, c1);
        sL[row][lane] = factor;
        sF[row][lane] = factor * fc;
        float e = 0.0f;
        if (row != lane) {
            int t4 = ti * 4 + tj;
            float r2 = rinv * rinv;
            float r6 = r2 * r2 * r2;
            e = (ref_A[t4] * __expf(ref_B[t4] * (ref_mu[t4] - R)) -
                 ref_C[t4] * r6 - ref_D[t4] * (r6 * r2)) * fc;
        }
        e2b[r] = e;
    }
#pragma unroll
    for (int m = 1; m < 64; m <<= 1) {
#pragma unroll
        for (int r = 0; r < 4; ++r) e2b[r] += __shfl_xor(e2b[r], m);
    }
    __syncthreads();

    // ---- phase D: wave 0 solves (fp64); waves 1-15 copy node_feats ----------
    if (wv == 0) {
        const int i = tid;
        double Ld = (double)(s_diag[i] + sL[i][i]);
        double inv = 1.0 / Ld;
        double au = 1.0;
        double av = (double)kappa[(g << 6) + i];
        double my_u = 0.0, my_v = 0.0;
        for (int j = 0; j < 64; ++j) {
            double ij = bcast_d(inv, j);
            double uj = bcast_d(au, j) * ij;
            double vj = bcast_d(av, j) * ij;
            if (i == j) { my_u = uj; my_v = vj; }
            if (i > j) {
                double Lij = (double)sL[i][j];
                au -= Lij * uj;
                av -= Lij * vj;
            }
        }
        double Su = wave_sum_d(my_u);
        double Sv = wave_sum_d(my_v);
        double lam = Sv / Su;  // q = -v + (Sv/Su)u  => sum(q) = 0
        s_q[i] = (float)(-my_v + lam * my_u);
    } else {
        // 4096 float2 per graph (64 rows x 64 float2), 960 threads
        for (int t2 = tid - 64; t2 < 4096; t2 += 960) {
            int row = t2 >> 6, c = t2 & 63;
            float2 v = ((const float2*)nf_in)[(((g << 6) + row) << 6) + c];
            *(float2*)(out + OUT_NF + (size_t)((g << 6) + row) * 130 + c * 2) = v;
        }
    }
    __syncthreads();

    // ---- phase E: matvec row sums + epilogue --------------------------------
    const float qj = s_q[lane];
    float pr[4], wr[4];
#pragma unroll
    for (int r = 0; r < 4; ++r) {
        const int row = (wv << 2) + r;
        pr[r] = sF[row][lane] * qj;
        wr[r] = sL[row][lane] * qj;
    }
#pragma unroll
    for (int m = 1; m < 64; m <<= 1) {
#pragma unroll
        for (int r = 0; r < 4; ++r) {
            pr[r] += __shfl_xor(pr[r], m);
            wr[r] += __shfl_xor(wr[r], m);
        }
    }
    float acc = 0.0f;
#pragma unroll
    for (int r = 0; r < 4; ++r) {
        const int row = (wv << 2) + r;
        const float q = s_q[row];
        const float sgi = __shfl(sgj, row);
        if (lane == 0) {
            float coef = 0.5f / (sgi * SQRT_PI);
            float aEel = q * (wr[r] + coef * q);
            float e2 = 0.5f * e2b[r];
            out[OUT_NODEE + (g << 6) + row] = aEel + e2 + s_ash[row];
            out[OUT_Q + (g << 6) + row] = q;
            size_t nfb = OUT_NF + (size_t)((g << 6) + row) * 130;
            out[nfb + 128] = q;
            out[nfb + 129] = pr[r];
            acc += aEel + e2;
        }
    }
    if (lane == 0) s_red[wv] = acc;
    __syncthreads();
    if (tid == 0) {
        float s = 0.0f;
#pragma unroll
        for (int k = 0; k < 16; ++k) s += s_red[k];
        out[OUT_ETOT + g] = s + short_e[g];
    }
}

extern "C" void kernel_launch(void* const* d_in, const int* in_sizes, int n_in,
                              void* d_out, int out_size, void* d_ws, size_t ws_size,
                              hipStream_t stream) {
    const float* node_attrs = (const float*)d_in[1];
    const int* edge_index = (const int*)d_in[2];
    const float* edge_length = (const float*)d_in[3];
    const float* kappa = (const float*)d_in[4];
    const float* node_feats = (const float*)d_in[5];
    const float* ref_eta = (const float*)d_in[6];
    const float* ref_log_sigma = (const float*)d_in[7];
    const float* ref_A = (const float*)d_in[8];
    const float* ref_B = (const float*)d_in[9];
    const float* ref_C = (const float*)d_in[10];
    const float* ref_D = (const float*)d_in[11];
    const float* ref_mu = (const float*)d_in[12];
    const float* short_energy = (const float*)d_in[13];
    const float* atomic_short = (const float*)d_in[14];

    k_main<<<G, 1024, 0, stream>>>(edge_index, edge_length, node_attrs, kappa,
                                   ref_eta, ref_log_sigma, ref_A, ref_B, ref_C,
                                   ref_D, ref_mu, short_energy, atomic_short,
                                   node_feats, (float*)d_out);
}